// Round 8
// baseline (226.631 us; speedup 1.0000x reference)
//
#include <hip/hip_runtime.h>
#include <hip/hip_fp16.h>

#define D_MODEL 128
#define NREP 8
#define FC 32     // edge-range chunks for LDS histogram / counting sort
#define WCB 8     // extra blocks appended to hist launch for the Wc precompute

// ---------------------------------------------------------------------------
// Edge dtype sniff: first 8 entries as int64 all in [0,2^31) => genuine int64.
// ---------------------------------------------------------------------------
__device__ __forceinline__ bool sniff_i64(const void* ei) {
    const long long* p64 = (const long long*)ei;
    bool f64 = true;
#pragma unroll
    for (int i = 0; i < 8; ++i) {
        long long v = p64[i];
        f64 = f64 && (v >= 0 && v < (1LL << 31));
    }
    return f64;
}

__device__ __forceinline__ void load_edge(const void* ei, int e, int nE, bool f64,
                                          int& s, int& d) {
    if (f64) {
        const long long* p64 = (const long long*)ei;
        s = (int)p64[e];
        d = (int)p64[(size_t)nE + e];
    } else {
        const int* p32 = (const int*)ei;
        s = p32[e];
        d = p32[(size_t)nE + e];
    }
}

// ---------------------------------------------------------------------------
// Fused: [blocks 0..FC) packed LDS histogram (low16=src, high16=dst counts,
// chunk <= 20000 edges so no 16-bit overflow) ; [blocks FC..FC+WCB)
// Wc = W1@W2 and g = b1@W2 precompute (independent work, same launch).
// ---------------------------------------------------------------------------
__global__ __launch_bounds__(1024) void hist_wc_kernel(const void* __restrict__ ei,
                                                       unsigned int* __restrict__ Cpk,
                                                       const float* __restrict__ W,
                                                       const float* __restrict__ b,
                                                       float* __restrict__ wc,
                                                       int nE, int n) {
    if (blockIdx.x >= FC) {
        int gid = (blockIdx.x - FC) * 1024 + threadIdx.x;
        const float* W2 = W + 128 * 128;
        for (int g = gid; g < 129 * 128; g += WCB * 1024) {
            int r = g >> 7, j = g & 127;
            const float* lhs = (r < 128) ? (W + (size_t)r * 128) : b;
            float acc = 0.f;
#pragma unroll 4
            for (int k = 0; k < 128; ++k) acc = fmaf(lhs[k], W2[(size_t)k * 128 + j], acc);
            wc[g] = acc;
        }
        return;
    }
    extern __shared__ unsigned int h[];
    bool f64 = sniff_i64(ei);
    int chunk = blockIdx.x;
    for (int i = threadIdx.x; i < n; i += 1024) h[i] = 0;
    __syncthreads();
    int ech = (nE + FC - 1) / FC;
    int e0 = chunk * ech;
    int e1 = min(nE, e0 + ech);
    if (f64) {
        const long long* p64 = (const long long*)ei;
        for (int e = e0 + threadIdx.x; e < e1; e += 1024) {
            atomicAdd(&h[(int)p64[e]], 1u);
            atomicAdd(&h[(int)p64[(size_t)nE + e]], 0x10000u);
        }
    } else {
        const int* p32 = (const int*)ei;
        for (int e = e0 + threadIdx.x; e < e1; e += 1024) {
            atomicAdd(&h[p32[e]], 1u);
            atomicAdd(&h[p32[(size_t)nE + e]], 0x10000u);
        }
    }
    __syncthreads();
    unsigned int* C = Cpk + (size_t)chunk * n;
    for (int i = threadIdx.x; i < n; i += 1024) C[i] = h[i];
}

// ---------------------------------------------------------------------------
// Fused scanA + xcvt: per node sum packed chunks -> degree factors, emit
// per-block partial sum of deg_in, then convert this block's 1024 rows:
// xh = fp16(a[row] * x[row]).
// ---------------------------------------------------------------------------
__global__ __launch_bounds__(1024) void scanA_xcvt_kernel(const unsigned int* __restrict__ Cpk,
                                                          const float* __restrict__ x,
                                                          float* __restrict__ a,
                                                          float* __restrict__ bfac,
                                                          float* __restrict__ ab,
                                                          int* __restrict__ deg_in,
                                                          int* __restrict__ part,
                                                          float2* __restrict__ xh, int n) {
    __shared__ int wsum[16];
    __shared__ float sh_a[1024];
    int tid = threadIdx.x;
    int i = blockIdx.x * 1024 + tid;
    int lane = tid & 63, wid = tid >> 6;
    int din = 0;
    float fa = 0.f;
    if (i < n) {
        int dout = 0;
#pragma unroll 8
        for (int c = 0; c < FC; ++c) {
            unsigned int w = Cpk[(size_t)c * n + i];
            dout += (int)(w & 0xFFFFu);
            din += (int)(w >> 16);
        }
        fa = rsqrtf((float)max(dout, 1));
        float fb = rsqrtf((float)max(din, 1));
        a[i] = fa;
        bfac[i] = fb;
        ab[i] = fa * fb;
        deg_in[i] = din;
    }
    sh_a[tid] = fa;
    int v = din;
#pragma unroll
    for (int d = 32; d > 0; d >>= 1) v += __shfl_down(v, d, 64);
    if (lane == 0) wsum[wid] = v;
    __syncthreads();
    if (tid == 0) {
        int s = 0;
#pragma unroll
        for (int w = 0; w < 16; ++w) s += wsum[w];
        part[blockIdx.x] = s;
    }
    int rows_in_block = min(1024, n - blockIdx.x * 1024);
    if (rows_in_block <= 0) return;
    int total = rows_in_block * 32;
    const float4* xb = (const float4*)(x + (size_t)blockIdx.x * 1024 * D_MODEL);
    float2* xhb = xh + (size_t)blockIdx.x * 1024 * 32;
    for (int t = tid; t < total; t += 1024) {
        int rl = t >> 5;
        float s = sh_a[rl];
        float4 vv = xb[t];
        union { __half2 h2[2]; float2 f2; } u;
        u.h2[0] = __floats2half2_rn(s * vv.x, s * vv.y);
        u.h2[1] = __floats2half2_rn(s * vv.z, s * vv.w);
        xhb[t] = u.f2;
    }
}

// ---------------------------------------------------------------------------
// Fused scanB + scanC + base: each block serially sums prior blocks'
// partials (<=40 adds), block-local exclusive scan -> offs, plus per-chunk
// counting-sort cursors base[c][i].
// ---------------------------------------------------------------------------
__global__ __launch_bounds__(1024) void scanBC_kernel(const int* __restrict__ deg,
                                                      const int* __restrict__ part,
                                                      const unsigned int* __restrict__ Cpk,
                                                      int* __restrict__ offs,
                                                      int* __restrict__ base, int n) {
    __shared__ int wsum[16];
    __shared__ int blk_prefix;
    int tid = threadIdx.x;
    int i = blockIdx.x * 1024 + tid;
    int lane = tid & 63, wid = tid >> 6;
    if (tid == 0) {
        int acc = 0;
        for (int j = 0; j < (int)blockIdx.x; ++j) acc += part[j];
        blk_prefix = acc;
    }
    int v = (i < n) ? deg[i] : 0;
    int s = v;
#pragma unroll
    for (int d = 1; d < 64; d <<= 1) {
        int t = __shfl_up(s, d, 64);
        if (lane >= d) s += t;
    }
    if (lane == 63) wsum[wid] = s;
    __syncthreads();
    if (wid == 0) {
        int wsv = (lane < 16) ? wsum[lane] : 0;
#pragma unroll
        for (int d = 1; d < 16; d <<= 1) {
            int t = __shfl_up(wsv, d, 16);
            if ((lane & 15) >= d) wsv += t;
        }
        if (lane < 16) wsum[lane] = wsv;
    }
    __syncthreads();
    int pfx = blk_prefix + ((wid > 0) ? wsum[wid - 1] : 0);
    int incl = pfx + s;
    if (i < n) {
        int run = incl - v;          // exclusive prefix
        offs[i] = run;
        if (i == n - 1) offs[n] = incl;
#pragma unroll 8
        for (int c = 0; c < FC; ++c) {
            base[(size_t)c * n + i] = run;
            run += (int)(Cpk[(size_t)c * n + i] >> 16);
        }
    }
}

// ---------------------------------------------------------------------------
// Counting-sort fill: per-chunk LDS cursors, scattered 4B stores only.
// ---------------------------------------------------------------------------
__global__ __launch_bounds__(1024) void fill_lds_kernel(const void* __restrict__ ei,
                                                        const int* __restrict__ base,
                                                        int* __restrict__ csr_src,
                                                        int nE, int n) {
    extern __shared__ int cur[];
    bool f64 = sniff_i64(ei);
    int chunk = blockIdx.x;
    for (int i = threadIdx.x; i < n; i += 1024) cur[i] = base[(size_t)chunk * n + i];
    __syncthreads();
    int ech = (nE + FC - 1) / FC;
    int e0 = chunk * ech;
    int e1 = min(nE, e0 + ech);
    for (int e = e0 + threadIdx.x; e < e1; e += 1024) {
        int s, d;
        load_edge(ei, e, nE, f64, s, d);
        int slot = atomicAdd(&cur[d], 1);
        csr_src[slot] = s;
    }
}

// ---------------------------------------------------------------------------
// Quarter-feature gather: phase q reads only a 2.56MB column-slice of the
// row table (fits in one XCD's 4MB L2; each edge touches exactly one 64B
// line). Wave = 4 edge-slots x 16 feature-lanes (half2); cross-slot
// __shfl_xor(32/16) reduce; lanes 0-15 write the 64B output slice.
// blockIdx is quarter-major so resident blocks sweep q=0..3 in phase.
// MODE 0: out = fp16(ab[v]*sum). MODE 1: out = fp16(sum); q==0 also
// computes c[v] = bfac[v]*sum(a[src]).
// ---------------------------------------------------------------------------
template <int MODE>
__global__ __launch_bounds__(256) void aggq_kernel(const __half2* __restrict__ rows_in,
                                                   const int* __restrict__ offs,
                                                   const int* __restrict__ csr,
                                                   const float* __restrict__ ab,
                                                   const float* __restrict__ bfac,
                                                   const float* __restrict__ a_arr,
                                                   __half2* __restrict__ out_rows,
                                                   float* __restrict__ c_out,
                                                   int n, int nbq) {
    int bid = blockIdx.x;
    int q = bid / nbq;
    int nb = bid - q * nbq;
    int node = nb * 4 + (threadIdx.x >> 6);
    if (node >= n) return;
    node = __builtin_amdgcn_readfirstlane(node);
    int lane = threadIdx.x & 63;
    int g = lane >> 4;    // edge slot 0..3
    int f = lane & 15;    // half2 feature within quarter
    int beg = offs[node], end = offs[node + 1];
    const __half2* tb = rows_in + q * 16 + f;
    float ax = 0.f, ay = 0.f, cs = 0.f;
    int e = beg + g;
    for (; e + 4 < end; e += 8) {       // 2 edges per lane in flight
        int s0 = csr[e];
        int s1 = csr[e + 4];
        float2 f0 = __half22float2(tb[(size_t)s0 * 64]);
        float2 f1 = __half22float2(tb[(size_t)s1 * 64]);
        ax += f0.x + f1.x;
        ay += f0.y + f1.y;
        if (MODE == 1 && f == 0) cs += a_arr[s0] + a_arr[s1];
    }
    if (e < end) {
        int s0 = csr[e];
        float2 f0 = __half22float2(tb[(size_t)s0 * 64]);
        ax += f0.x;
        ay += f0.y;
        if (MODE == 1 && f == 0) cs += a_arr[s0];
    }
    ax += __shfl_xor(ax, 32); ax += __shfl_xor(ax, 16);
    ay += __shfl_xor(ay, 32); ay += __shfl_xor(ay, 16);
    if (MODE == 0) {
        if (lane < 16) {
            float sc = ab[node];
            out_rows[(size_t)node * 64 + q * 16 + lane] = __floats2half2_rn(sc * ax, sc * ay);
        }
    } else {
        if (lane < 16)
            out_rows[(size_t)node * 64 + q * 16 + lane] = __floats2half2_rn(ax, ay);
        if (q == 0) {
            cs += __shfl_xor(cs, 32); cs += __shfl_xor(cs, 16);
            if (lane == 0) c_out[node] = bfac[node] * cs;
        }
    }
}

// ---------------------------------------------------------------------------
// Final GEMM + epilogue: out = bfac[row]*(t2raw @ Wc) + c[row]*g + b2
// t2raw fp16 [N][128]; 32 rows/block, 4x4 register blocking.
// ---------------------------------------------------------------------------
__global__ __launch_bounds__(256) void gemm_final_kernel(const __half2* __restrict__ A2,
                                                         const float* __restrict__ wc,
                                                         const float* __restrict__ bfac,
                                                         const float* __restrict__ c_arr,
                                                         const float* __restrict__ b2,
                                                         float* __restrict__ out, int nRows) {
    __shared__ float Ws[32][128];
    __shared__ float At[32][36];
    int tid = threadIdx.x;
    int tc = tid & 31;
    int tr = tid >> 5;
    int row0 = blockIdx.x * 32;
    float acc[4][4] = {};

    for (int k0 = 0; k0 < D_MODEL; k0 += 32) {
        __syncthreads();
        {
            const float4* Wg = (const float4*)(wc + (size_t)k0 * D_MODEL);
            float4* WsV = (float4*)&Ws[0][0];
#pragma unroll
            for (int i = 0; i < 4; ++i) WsV[tid + 256 * i] = Wg[tid + 256 * i];
        }
        int k0h = k0 >> 1;
#pragma unroll
        for (int i = 0; i < 2; ++i) {
            int lin = tid + 256 * i;      // 0..511
            int r = lin >> 4;             // 0..31
            int h = lin & 15;
            int row = row0 + r;
            __half2 v = (row < nRows) ? A2[(size_t)row * 64 + k0h + h]
                                      : __floats2half2_rn(0.f, 0.f);
            float2 f = __half22float2(v);
            At[2 * h][r] = f.x;
            At[2 * h + 1][r] = f.y;
        }
        __syncthreads();
#pragma unroll
        for (int kk = 0; kk < 32; ++kk) {
            float4 w4 = *(const float4*)&Ws[kk][4 * tc];
            float4 a4 = *(const float4*)&At[kk][4 * tr];
            float wv[4] = {w4.x, w4.y, w4.z, w4.w};
            float av[4] = {a4.x, a4.y, a4.z, a4.w};
#pragma unroll
            for (int i = 0; i < 4; ++i)
#pragma unroll
                for (int j = 0; j < 4; ++j)
                    acc[i][j] = fmaf(av[i], wv[j], acc[i][j]);
        }
    }
    float4 g4 = *(const float4*)(wc + 128 * 128 + 4 * tc);
    float4 b4 = *(const float4*)(b2 + 4 * tc);
#pragma unroll
    for (int i = 0; i < 4; ++i) {
        int row = row0 + 4 * tr + i;
        if (row < nRows) {
            float bf = bfac[row];
            float cv = c_arr[row];
            float4 o;
            o.x = bf * acc[i][0] + cv * g4.x + b4.x;
            o.y = bf * acc[i][1] + cv * g4.y + b4.y;
            o.z = bf * acc[i][2] + cv * g4.z + b4.z;
            o.w = bf * acc[i][3] + cv * g4.w + b4.w;
            *(float4*)(out + (size_t)row * D_MODEL + 4 * tc) = o;
        }
    }
}

// ---------------------------------------------------------------------------
// Fallback path (N too big for LDS histogram): global-atomic degrees + fill
// ---------------------------------------------------------------------------
__global__ void prep_kernel(const void* __restrict__ ei, int* __restrict__ rep_out,
                            int* __restrict__ rep_in, int nE, int n) {
    bool f64 = sniff_i64(ei);
    int e = blockIdx.x * blockDim.x + threadIdx.x;
    if (e >= nE) return;
    int s, d;
    load_edge(ei, e, nE, f64, s, d);
    int rep = blockIdx.x & (NREP - 1);
    atomicAdd(&rep_out[(size_t)rep * n + s], 1);
    atomicAdd(&rep_in[(size_t)rep * n + d], 1);
}

__global__ void deg_reduce_rep_kernel(const int* __restrict__ rep_out,
                                      const int* __restrict__ rep_in,
                                      float* __restrict__ a, float* __restrict__ bfac,
                                      float* __restrict__ ab, int* __restrict__ deg_in,
                                      int n) {
    int v = blockIdx.x * blockDim.x + threadIdx.x;
    if (v >= n) return;
    int dout = 0, din = 0;
#pragma unroll
    for (int r = 0; r < NREP; ++r) {
        dout += rep_out[(size_t)r * n + v];
        din += rep_in[(size_t)r * n + v];
    }
    float fa = rsqrtf((float)max(dout, 1));
    float fb = rsqrtf((float)max(din, 1));
    a[v] = fa;
    bfac[v] = fb;
    ab[v] = fa * fb;
    deg_in[v] = din;
}

__global__ __launch_bounds__(1024) void scanA_plain_kernel(const int* __restrict__ deg,
                                                           int* __restrict__ part, int n) {
    __shared__ int wsum[16];
    int i = blockIdx.x * 1024 + threadIdx.x;
    int lane = threadIdx.x & 63, wid = threadIdx.x >> 6;
    int v = (i < n) ? deg[i] : 0;
#pragma unroll
    for (int d = 32; d > 0; d >>= 1) v += __shfl_down(v, d, 64);
    if (lane == 0) wsum[wid] = v;
    __syncthreads();
    if (threadIdx.x == 0) {
        int s = 0;
#pragma unroll
        for (int w = 0; w < 16; ++w) s += wsum[w];
        part[blockIdx.x] = s;
    }
}

__global__ __launch_bounds__(1024) void scanC_plain_kernel(const int* __restrict__ deg,
                                                           const int* __restrict__ part,
                                                           int* __restrict__ offs, int n) {
    __shared__ int wsum[16];
    __shared__ int blk_prefix;
    int i = blockIdx.x * 1024 + threadIdx.x;
    int lane = threadIdx.x & 63, wid = threadIdx.x >> 6;
    if (threadIdx.x == 0) {
        int acc = 0;
        for (int j = 0; j < (int)blockIdx.x; ++j) acc += part[j];
        blk_prefix = acc;
    }
    int v = (i < n) ? deg[i] : 0;
    int s = v;
#pragma unroll
    for (int d = 1; d < 64; d <<= 1) {
        int t = __shfl_up(s, d, 64);
        if (lane >= d) s += t;
    }
    if (lane == 63) wsum[wid] = s;
    __syncthreads();
    if (wid == 0) {
        int wsv = (lane < 16) ? wsum[lane] : 0;
#pragma unroll
        for (int d = 1; d < 16; d <<= 1) {
            int t = __shfl_up(wsv, d, 16);
            if ((lane & 15) >= d) wsv += t;
        }
        if (lane < 16) wsum[lane] = wsv;
    }
    __syncthreads();
    int pfx = blk_prefix + ((wid > 0) ? wsum[wid - 1] : 0);
    int incl = pfx + s;
    if (i < n) {
        offs[i] = incl - v;
        if (i == n - 1) offs[n] = incl;
    }
}

__global__ void fill_kernel(const void* __restrict__ ei, const int* __restrict__ offs,
                            int* __restrict__ cursor, int* __restrict__ csr_src, int nE) {
    bool f64 = sniff_i64(ei);
    int e = blockIdx.x * blockDim.x + threadIdx.x;
    if (e >= nE) return;
    int s, d;
    load_edge(ei, e, nE, f64, s, d);
    int slot = offs[d] + atomicAdd(&cursor[d], 1);
    csr_src[slot] = s;
}

__global__ void xcvt_kernel(const float* __restrict__ x, const float* __restrict__ a,
                            float2* __restrict__ xh, int n4) {
    int idx = blockIdx.x * blockDim.x + threadIdx.x;
    if (idx >= n4) return;
    int row = idx >> 5;
    float s = a[row];
    float4 v = ((const float4*)x)[idx];
    union { __half2 h2[2]; float2 f2; } uu;
    uu.h2[0] = __floats2half2_rn(s * v.x, s * v.y);
    uu.h2[1] = __floats2half2_rn(s * v.z, s * v.w);
    xh[idx] = uu.f2;
}

__global__ void wc_plain_kernel(const float* __restrict__ W, const float* __restrict__ b,
                                float* __restrict__ wc) {
    int gid = blockIdx.x * blockDim.x + threadIdx.x;
    if (gid >= 129 * 128) return;
    int r = gid >> 7, j = gid & 127;
    const float* W2 = W + 128 * 128;
    const float* lhs = (r < 128) ? (W + (size_t)r * 128) : b;
    float acc = 0.f;
#pragma unroll 4
    for (int k = 0; k < 128; ++k) acc = fmaf(lhs[k], W2[(size_t)k * 128 + j], acc);
    wc[gid] = acc;
}

// ---------------------------------------------------------------------------
extern "C" void kernel_launch(void* const* d_in, const int* in_sizes, int n_in,
                              void* d_out, int out_size, void* d_ws, size_t ws_size,
                              hipStream_t stream) {
    const float* x = (const float*)d_in[0];
    const float* W = (const float*)d_in[1];
    const float* b = (const float*)d_in[2];
    const void* ei = d_in[3];
    const int D = D_MODEL;
    int N = in_sizes[0] / D;
    int E = in_sizes[3] / 2;
    float* out = (float*)d_out;

    char* p = (char*)d_ws;
    size_t off = 0;
    auto take = [&](size_t bytes) {
        void* r = p + off;
        off += (bytes + 255) & ~(size_t)255;
        return r;
    };
    __half2* xh   = (__half2*)take((size_t)N * D * 2);
    __half2* u    = (__half2*)take((size_t)N * D * 2);
    int* csr_src  = (int*)take((size_t)E * 4);
    float* a_arr  = (float*)take((size_t)N * 4);
    float* bfac   = (float*)take((size_t)N * 4);
    float* ab     = (float*)take((size_t)N * 4);
    float* c_arr  = (float*)take((size_t)N * 4);
    int* deg_in   = (int*)take((size_t)N * 4);
    int* offs     = (int*)take((size_t)(N + 1) * 4);
    int* cursor   = (int*)take((size_t)N * 4);
    int* part     = (int*)take(256 * 4);
    float* wc     = (float*)take((size_t)129 * 128 * 4);
    unsigned int* Cpk = (unsigned int*)take((size_t)FC * N * 4);
    int* base     = (int*)take((size_t)FC * N * 4);
    size_t lds_need = off;
    __half2* t2 = xh;   // alias: xh dead once agg<0> completes

    size_t lds_bytes = (size_t)N * 4;
    bool use_lds = (lds_bytes <= 160000) && (lds_need <= ws_size);

    int eb = (E + 255) / 256;
    int G = (N + 1023) / 1024;

    if (use_lds) {
        hist_wc_kernel<<<FC + WCB, 1024, lds_bytes, stream>>>(ei, Cpk, W, b, wc, E, N);
        scanA_xcvt_kernel<<<G, 1024, 0, stream>>>(Cpk, x, a_arr, bfac, ab, deg_in,
                                                  part, (float2*)xh, N);
        scanBC_kernel<<<G, 1024, 0, stream>>>(deg_in, part, Cpk, offs, base, N);
        fill_lds_kernel<<<FC, 1024, lds_bytes, stream>>>(ei, base, csr_src, E, N);
    } else {
        int* rep_out = (int*)Cpk;
        int* rep_in  = (int*)base;
        if (lds_need > ws_size) {
            rep_out = (int*)u;
            rep_in  = (int*)((char*)u + (size_t)NREP * N * 4);
        }
        hipMemsetAsync(rep_out, 0, (size_t)NREP * N * 4, stream);
        hipMemsetAsync(rep_in, 0, (size_t)NREP * N * 4, stream);
        hipMemsetAsync(cursor, 0, (size_t)N * 4, stream);
        wc_plain_kernel<<<(129 * 128 + 255) / 256, 256, 0, stream>>>(W, b, wc);
        prep_kernel<<<eb, 256, 0, stream>>>(ei, rep_out, rep_in, E, N);
        deg_reduce_rep_kernel<<<(N + 255) / 256, 256, 0, stream>>>(rep_out, rep_in, a_arr,
                                                                   bfac, ab, deg_in, N);
        scanA_plain_kernel<<<G, 1024, 0, stream>>>(deg_in, part, N);
        scanC_plain_kernel<<<G, 1024, 0, stream>>>(deg_in, part, offs, N);
        fill_kernel<<<eb, 256, 0, stream>>>(ei, offs, cursor, csr_src, E);
        int n4 = N * (D / 4);
        xcvt_kernel<<<(n4 + 255) / 256, 256, 0, stream>>>(x, a_arr, (float2*)xh, n4);
    }

    int nbq = (N + 3) / 4;          // node-blocks per quarter phase
    aggq_kernel<0><<<4 * nbq, 256, 0, stream>>>(xh, offs, csr_src, ab, bfac, a_arr,
                                                u, c_arr, N, nbq);
    aggq_kernel<1><<<4 * nbq, 256, 0, stream>>>(u, offs, csr_src, ab, bfac, a_arr,
                                                t2, c_arr, N, nbq);
    gemm_final_kernel<<<(N + 31) / 32, 256, 0, stream>>>(t2, wc, bfac, c_arr,
                                                         b + 128, out, N);
}

// Round 9
// 148.569 us; speedup vs baseline: 1.5254x; 1.5254x over previous
//
#include <hip/hip_runtime.h>
#include <hip/hip_fp16.h>

#define D_MODEL 128
#define NREP 8
#define FC 32     // edge-range chunks for LDS histogram / counting sort
#define WCB 8     // extra blocks appended to hist launch for the Wc precompute

// ---------------------------------------------------------------------------
// Edge dtype sniff: first 8 entries as int64 all in [0,2^31) => genuine int64.
// ---------------------------------------------------------------------------
__device__ __forceinline__ bool sniff_i64(const void* ei) {
    const long long* p64 = (const long long*)ei;
    bool f64 = true;
#pragma unroll
    for (int i = 0; i < 8; ++i) {
        long long v = p64[i];
        f64 = f64 && (v >= 0 && v < (1LL << 31));
    }
    return f64;
}

__device__ __forceinline__ void load_edge(const void* ei, int e, int nE, bool f64,
                                          int& s, int& d) {
    if (f64) {
        const long long* p64 = (const long long*)ei;
        s = (int)p64[e];
        d = (int)p64[(size_t)nE + e];
    } else {
        const int* p32 = (const int*)ei;
        s = p32[e];
        d = p32[(size_t)nE + e];
    }
}

// ---------------------------------------------------------------------------
// Fused: [blocks 0..FC) packed LDS histogram (low16=src, high16=dst counts,
// chunk <= 20000 edges so no 16-bit overflow) ; [blocks FC..FC+WCB)
// Wc = W1@W2 and g = b1@W2 precompute (independent work, same launch).
// ---------------------------------------------------------------------------
__global__ __launch_bounds__(1024) void hist_wc_kernel(const void* __restrict__ ei,
                                                       unsigned int* __restrict__ Cpk,
                                                       const float* __restrict__ W,
                                                       const float* __restrict__ b,
                                                       float* __restrict__ wc,
                                                       int nE, int n) {
    if (blockIdx.x >= FC) {
        int gid = (blockIdx.x - FC) * 1024 + threadIdx.x;
        const float* W2 = W + 128 * 128;
        for (int g = gid; g < 129 * 128; g += WCB * 1024) {
            int r = g >> 7, j = g & 127;
            const float* lhs = (r < 128) ? (W + (size_t)r * 128) : b;
            float acc = 0.f;
#pragma unroll 4
            for (int k = 0; k < 128; ++k) acc = fmaf(lhs[k], W2[(size_t)k * 128 + j], acc);
            wc[g] = acc;
        }
        return;
    }
    extern __shared__ unsigned int h[];
    bool f64 = sniff_i64(ei);
    int chunk = blockIdx.x;
    for (int i = threadIdx.x; i < n; i += 1024) h[i] = 0;
    __syncthreads();
    int ech = (nE + FC - 1) / FC;
    int e0 = chunk * ech;
    int e1 = min(nE, e0 + ech);
    if (f64) {
        const long long* p64 = (const long long*)ei;
        for (int e = e0 + threadIdx.x; e < e1; e += 1024) {
            atomicAdd(&h[(int)p64[e]], 1u);
            atomicAdd(&h[(int)p64[(size_t)nE + e]], 0x10000u);
        }
    } else {
        const int* p32 = (const int*)ei;
        for (int e = e0 + threadIdx.x; e < e1; e += 1024) {
            atomicAdd(&h[p32[e]], 1u);
            atomicAdd(&h[p32[(size_t)nE + e]], 0x10000u);
        }
    }
    __syncthreads();
    unsigned int* C = Cpk + (size_t)chunk * n;
    for (int i = threadIdx.x; i < n; i += 1024) C[i] = h[i];
}

// ---------------------------------------------------------------------------
// Fused scanA + xcvt: per node sum packed chunks -> degree factors, emit
// per-block partial sum of deg_in, then convert this block's 1024 rows:
// xh = fp16(a[row] * x[row]).
// ---------------------------------------------------------------------------
__global__ __launch_bounds__(1024) void scanA_xcvt_kernel(const unsigned int* __restrict__ Cpk,
                                                          const float* __restrict__ x,
                                                          float* __restrict__ a,
                                                          float* __restrict__ bfac,
                                                          float* __restrict__ ab,
                                                          int* __restrict__ deg_in,
                                                          int* __restrict__ part,
                                                          float2* __restrict__ xh, int n) {
    __shared__ int wsum[16];
    __shared__ float sh_a[1024];
    int tid = threadIdx.x;
    int i = blockIdx.x * 1024 + tid;
    int lane = tid & 63, wid = tid >> 6;
    int din = 0;
    float fa = 0.f;
    if (i < n) {
        int dout = 0;
#pragma unroll 8
        for (int c = 0; c < FC; ++c) {
            unsigned int w = Cpk[(size_t)c * n + i];
            dout += (int)(w & 0xFFFFu);
            din += (int)(w >> 16);
        }
        fa = rsqrtf((float)max(dout, 1));
        float fb = rsqrtf((float)max(din, 1));
        a[i] = fa;
        bfac[i] = fb;
        ab[i] = fa * fb;
        deg_in[i] = din;
    }
    sh_a[tid] = fa;
    int v = din;
#pragma unroll
    for (int d = 32; d > 0; d >>= 1) v += __shfl_down(v, d, 64);
    if (lane == 0) wsum[wid] = v;
    __syncthreads();
    if (tid == 0) {
        int s = 0;
#pragma unroll
        for (int w = 0; w < 16; ++w) s += wsum[w];
        part[blockIdx.x] = s;
    }
    int rows_in_block = min(1024, n - blockIdx.x * 1024);
    if (rows_in_block <= 0) return;
    int total = rows_in_block * 32;
    const float4* xb = (const float4*)(x + (size_t)blockIdx.x * 1024 * D_MODEL);
    float2* xhb = xh + (size_t)blockIdx.x * 1024 * 32;
    for (int t = tid; t < total; t += 1024) {
        int rl = t >> 5;
        float s = sh_a[rl];
        float4 vv = xb[t];
        union { __half2 h2[2]; float2 f2; } u;
        u.h2[0] = __floats2half2_rn(s * vv.x, s * vv.y);
        u.h2[1] = __floats2half2_rn(s * vv.z, s * vv.w);
        xhb[t] = u.f2;
    }
}

// ---------------------------------------------------------------------------
// Fused scanB + scanC + base: each block serially sums prior blocks'
// partials (<=40 adds), block-local exclusive scan -> offs, plus per-chunk
// counting-sort cursors base[c][i].
// ---------------------------------------------------------------------------
__global__ __launch_bounds__(1024) void scanBC_kernel(const int* __restrict__ deg,
                                                      const int* __restrict__ part,
                                                      const unsigned int* __restrict__ Cpk,
                                                      int* __restrict__ offs,
                                                      int* __restrict__ base, int n) {
    __shared__ int wsum[16];
    __shared__ int blk_prefix;
    int tid = threadIdx.x;
    int i = blockIdx.x * 1024 + tid;
    int lane = tid & 63, wid = tid >> 6;
    if (tid == 0) {
        int acc = 0;
        for (int j = 0; j < (int)blockIdx.x; ++j) acc += part[j];
        blk_prefix = acc;
    }
    int v = (i < n) ? deg[i] : 0;
    int s = v;
#pragma unroll
    for (int d = 1; d < 64; d <<= 1) {
        int t = __shfl_up(s, d, 64);
        if (lane >= d) s += t;
    }
    if (lane == 63) wsum[wid] = s;
    __syncthreads();
    if (wid == 0) {
        int wsv = (lane < 16) ? wsum[lane] : 0;
#pragma unroll
        for (int d = 1; d < 16; d <<= 1) {
            int t = __shfl_up(wsv, d, 16);
            if ((lane & 15) >= d) wsv += t;
        }
        if (lane < 16) wsum[lane] = wsv;
    }
    __syncthreads();
    int pfx = blk_prefix + ((wid > 0) ? wsum[wid - 1] : 0);
    int incl = pfx + s;
    if (i < n) {
        int run = incl - v;          // exclusive prefix
        offs[i] = run;
        if (i == n - 1) offs[n] = incl;
#pragma unroll 8
        for (int c = 0; c < FC; ++c) {
            base[(size_t)c * n + i] = run;
            run += (int)(Cpk[(size_t)c * n + i] >> 16);
        }
    }
}

// ---------------------------------------------------------------------------
// Counting-sort fill: per-chunk LDS cursors, scattered 4B stores only.
// ---------------------------------------------------------------------------
__global__ __launch_bounds__(1024) void fill_lds_kernel(const void* __restrict__ ei,
                                                        const int* __restrict__ base,
                                                        int* __restrict__ csr_src,
                                                        int nE, int n) {
    extern __shared__ int cur[];
    bool f64 = sniff_i64(ei);
    int chunk = blockIdx.x;
    for (int i = threadIdx.x; i < n; i += 1024) cur[i] = base[(size_t)chunk * n + i];
    __syncthreads();
    int ech = (nE + FC - 1) / FC;
    int e0 = chunk * ech;
    int e1 = min(nE, e0 + ech);
    for (int e = e0 + threadIdx.x; e < e1; e += 1024) {
        int s, d;
        load_edge(ei, e, nE, f64, s, d);
        int slot = atomicAdd(&cur[d], 1);
        csr_src[slot] = s;
    }
}

// ---------------------------------------------------------------------------
// Gather-sum over fp16 rows, one wave per dst node, lane owns half2.
// Wave-uniform node -> csr index loads are scalar; 8 independent 256B row
// loads in flight per wave (MLP is the lever; VALUBusy ~5%).
// MODE 0: out = fp16(ab[v]*sum). MODE 1: out = fp16(sum), c[v]=bfac*sum(a[src]).
// ---------------------------------------------------------------------------
template <int MODE>
__global__ __launch_bounds__(256) void agg_kernel(const __half2* __restrict__ rows_in,
                                                  const int* __restrict__ offs,
                                                  const int* __restrict__ csr,
                                                  const float* __restrict__ ab,
                                                  const float* __restrict__ bfac,
                                                  const float* __restrict__ a_arr,
                                                  __half2* __restrict__ out_rows,
                                                  float* __restrict__ c_out, int n) {
    int node = blockIdx.x * 4 + (threadIdx.x >> 6);
    if (node >= n) return;
    node = __builtin_amdgcn_readfirstlane(node);  // wave-uniform -> scalar loads
    int lane = threadIdx.x & 63;
    const __half2* rl = rows_in + lane;
    int beg = offs[node], end = offs[node + 1];
    float ax0 = 0.f, ay0 = 0.f, ax1 = 0.f, ay1 = 0.f;
    float ax2 = 0.f, ay2 = 0.f, ax3 = 0.f, ay3 = 0.f;
    float cs = 0.f;
    int e = beg;
    for (; e + 7 < end; e += 8) {
        int s0 = csr[e],     s1 = csr[e + 1], s2 = csr[e + 2], s3 = csr[e + 3];
        int s4 = csr[e + 4], s5 = csr[e + 5], s6 = csr[e + 6], s7 = csr[e + 7];
        __half2 v0 = rl[(size_t)s0 * 64];
        __half2 v1 = rl[(size_t)s1 * 64];
        __half2 v2 = rl[(size_t)s2 * 64];
        __half2 v3 = rl[(size_t)s3 * 64];
        __half2 v4 = rl[(size_t)s4 * 64];
        __half2 v5 = rl[(size_t)s5 * 64];
        __half2 v6 = rl[(size_t)s6 * 64];
        __half2 v7 = rl[(size_t)s7 * 64];
        float2 f0 = __half22float2(v0), f1 = __half22float2(v1);
        float2 f2 = __half22float2(v2), f3 = __half22float2(v3);
        float2 f4 = __half22float2(v4), f5 = __half22float2(v5);
        float2 f6 = __half22float2(v6), f7 = __half22float2(v7);
        ax0 += f0.x + f4.x; ay0 += f0.y + f4.y;
        ax1 += f1.x + f5.x; ay1 += f1.y + f5.y;
        ax2 += f2.x + f6.x; ay2 += f2.y + f6.y;
        ax3 += f3.x + f7.x; ay3 += f3.y + f7.y;
        if (MODE == 1)
            cs += ((a_arr[s0] + a_arr[s1]) + (a_arr[s2] + a_arr[s3])) +
                  ((a_arr[s4] + a_arr[s5]) + (a_arr[s6] + a_arr[s7]));
    }
    for (; e + 1 < end; e += 2) {
        int s0 = csr[e], s1 = csr[e + 1];
        float2 f0 = __half22float2(rl[(size_t)s0 * 64]);
        float2 f1 = __half22float2(rl[(size_t)s1 * 64]);
        ax0 += f0.x; ay0 += f0.y;
        ax1 += f1.x; ay1 += f1.y;
        if (MODE == 1) cs += a_arr[s0] + a_arr[s1];
    }
    if (e < end) {
        int s0 = csr[e];
        float2 f0 = __half22float2(rl[(size_t)s0 * 64]);
        ax0 += f0.x; ay0 += f0.y;
        if (MODE == 1) cs += a_arr[s0];
    }
    float sx = (ax0 + ax1) + (ax2 + ax3);
    float sy = (ay0 + ay1) + (ay2 + ay3);
    if (MODE == 0) {
        float sc = ab[node];
        out_rows[(size_t)node * 64 + lane] = __floats2half2_rn(sc * sx, sc * sy);
    } else {
        out_rows[(size_t)node * 64 + lane] = __floats2half2_rn(sx, sy);
        if (lane == 0) c_out[node] = bfac[node] * cs;
    }
}

// ---------------------------------------------------------------------------
// Final GEMM + epilogue: out = bfac[row]*(t2raw @ Wc) + c[row]*g + b2
// t2raw fp16 [N][128]; 32 rows/block, 4x4 register blocking.
// ---------------------------------------------------------------------------
__global__ __launch_bounds__(256) void gemm_final_kernel(const __half2* __restrict__ A2,
                                                         const float* __restrict__ wc,
                                                         const float* __restrict__ bfac,
                                                         const float* __restrict__ c_arr,
                                                         const float* __restrict__ b2,
                                                         float* __restrict__ out, int nRows) {
    __shared__ float Ws[32][128];
    __shared__ float At[32][36];
    int tid = threadIdx.x;
    int tc = tid & 31;
    int tr = tid >> 5;
    int row0 = blockIdx.x * 32;
    float acc[4][4] = {};

    for (int k0 = 0; k0 < D_MODEL; k0 += 32) {
        __syncthreads();
        {
            const float4* Wg = (const float4*)(wc + (size_t)k0 * D_MODEL);
            float4* WsV = (float4*)&Ws[0][0];
#pragma unroll
            for (int i = 0; i < 4; ++i) WsV[tid + 256 * i] = Wg[tid + 256 * i];
        }
        int k0h = k0 >> 1;
#pragma unroll
        for (int i = 0; i < 2; ++i) {
            int lin = tid + 256 * i;      // 0..511
            int r = lin >> 4;             // 0..31
            int h = lin & 15;
            int row = row0 + r;
            __half2 v = (row < nRows) ? A2[(size_t)row * 64 + k0h + h]
                                      : __floats2half2_rn(0.f, 0.f);
            float2 f = __half22float2(v);
            At[2 * h][r] = f.x;
            At[2 * h + 1][r] = f.y;
        }
        __syncthreads();
#pragma unroll
        for (int kk = 0; kk < 32; ++kk) {
            float4 w4 = *(const float4*)&Ws[kk][4 * tc];
            float4 a4 = *(const float4*)&At[kk][4 * tr];
            float wv[4] = {w4.x, w4.y, w4.z, w4.w};
            float av[4] = {a4.x, a4.y, a4.z, a4.w};
#pragma unroll
            for (int i = 0; i < 4; ++i)
#pragma unroll
                for (int j = 0; j < 4; ++j)
                    acc[i][j] = fmaf(av[i], wv[j], acc[i][j]);
        }
    }
    float4 g4 = *(const float4*)(wc + 128 * 128 + 4 * tc);
    float4 b4 = *(const float4*)(b2 + 4 * tc);
#pragma unroll
    for (int i = 0; i < 4; ++i) {
        int row = row0 + 4 * tr + i;
        if (row < nRows) {
            float bf = bfac[row];
            float cv = c_arr[row];
            float4 o;
            o.x = bf * acc[i][0] + cv * g4.x + b4.x;
            o.y = bf * acc[i][1] + cv * g4.y + b4.y;
            o.z = bf * acc[i][2] + cv * g4.z + b4.z;
            o.w = bf * acc[i][3] + cv * g4.w + b4.w;
            *(float4*)(out + (size_t)row * D_MODEL + 4 * tc) = o;
        }
    }
}

// ---------------------------------------------------------------------------
// Fallback path (N too big for LDS histogram): global-atomic degrees + fill
// ---------------------------------------------------------------------------
__global__ void prep_kernel(const void* __restrict__ ei, int* __restrict__ rep_out,
                            int* __restrict__ rep_in, int nE, int n) {
    bool f64 = sniff_i64(ei);
    int e = blockIdx.x * blockDim.x + threadIdx.x;
    if (e >= nE) return;
    int s, d;
    load_edge(ei, e, nE, f64, s, d);
    int rep = blockIdx.x & (NREP - 1);
    atomicAdd(&rep_out[(size_t)rep * n + s], 1);
    atomicAdd(&rep_in[(size_t)rep * n + d], 1);
}

__global__ void deg_reduce_rep_kernel(const int* __restrict__ rep_out,
                                      const int* __restrict__ rep_in,
                                      float* __restrict__ a, float* __restrict__ bfac,
                                      float* __restrict__ ab, int* __restrict__ deg_in,
                                      int n) {
    int v = blockIdx.x * blockDim.x + threadIdx.x;
    if (v >= n) return;
    int dout = 0, din = 0;
#pragma unroll
    for (int r = 0; r < NREP; ++r) {
        dout += rep_out[(size_t)r * n + v];
        din += rep_in[(size_t)r * n + v];
    }
    float fa = rsqrtf((float)max(dout, 1));
    float fb = rsqrtf((float)max(din, 1));
    a[v] = fa;
    bfac[v] = fb;
    ab[v] = fa * fb;
    deg_in[v] = din;
}

__global__ __launch_bounds__(1024) void scanA_plain_kernel(const int* __restrict__ deg,
                                                           int* __restrict__ part, int n) {
    __shared__ int wsum[16];
    int i = blockIdx.x * 1024 + threadIdx.x;
    int lane = threadIdx.x & 63, wid = threadIdx.x >> 6;
    int v = (i < n) ? deg[i] : 0;
#pragma unroll
    for (int d = 32; d > 0; d >>= 1) v += __shfl_down(v, d, 64);
    if (lane == 0) wsum[wid] = v;
    __syncthreads();
    if (threadIdx.x == 0) {
        int s = 0;
#pragma unroll
        for (int w = 0; w < 16; ++w) s += wsum[w];
        part[blockIdx.x] = s;
    }
}

__global__ __launch_bounds__(1024) void scanC_plain_kernel(const int* __restrict__ deg,
                                                           const int* __restrict__ part,
                                                           int* __restrict__ offs, int n) {
    __shared__ int wsum[16];
    __shared__ int blk_prefix;
    int i = blockIdx.x * 1024 + threadIdx.x;
    int lane = threadIdx.x & 63, wid = threadIdx.x >> 6;
    if (threadIdx.x == 0) {
        int acc = 0;
        for (int j = 0; j < (int)blockIdx.x; ++j) acc += part[j];
        blk_prefix = acc;
    }
    int v = (i < n) ? deg[i] : 0;
    int s = v;
#pragma unroll
    for (int d = 1; d < 64; d <<= 1) {
        int t = __shfl_up(s, d, 64);
        if (lane >= d) s += t;
    }
    if (lane == 63) wsum[wid] = s;
    __syncthreads();
    if (wid == 0) {
        int wsv = (lane < 16) ? wsum[lane] : 0;
#pragma unroll
        for (int d = 1; d < 16; d <<= 1) {
            int t = __shfl_up(wsv, d, 16);
            if ((lane & 15) >= d) wsv += t;
        }
        if (lane < 16) wsum[lane] = wsv;
    }
    __syncthreads();
    int pfx = blk_prefix + ((wid > 0) ? wsum[wid - 1] : 0);
    int incl = pfx + s;
    if (i < n) {
        offs[i] = incl - v;
        if (i == n - 1) offs[n] = incl;
    }
}

__global__ void fill_kernel(const void* __restrict__ ei, const int* __restrict__ offs,
                            int* __restrict__ cursor, int* __restrict__ csr_src, int nE) {
    bool f64 = sniff_i64(ei);
    int e = blockIdx.x * blockDim.x + threadIdx.x;
    if (e >= nE) return;
    int s, d;
    load_edge(ei, e, nE, f64, s, d);
    int slot = offs[d] + atomicAdd(&cursor[d], 1);
    csr_src[slot] = s;
}

__global__ void xcvt_kernel(const float* __restrict__ x, const float* __restrict__ a,
                            float2* __restrict__ xh, int n4) {
    int idx = blockIdx.x * blockDim.x + threadIdx.x;
    if (idx >= n4) return;
    int row = idx >> 5;
    float s = a[row];
    float4 v = ((const float4*)x)[idx];
    union { __half2 h2[2]; float2 f2; } uu;
    uu.h2[0] = __floats2half2_rn(s * v.x, s * v.y);
    uu.h2[1] = __floats2half2_rn(s * v.z, s * v.w);
    xh[idx] = uu.f2;
}

__global__ void wc_plain_kernel(const float* __restrict__ W, const float* __restrict__ b,
                                float* __restrict__ wc) {
    int gid = blockIdx.x * blockDim.x + threadIdx.x;
    if (gid >= 129 * 128) return;
    int r = gid >> 7, j = gid & 127;
    const float* W2 = W + 128 * 128;
    const float* lhs = (r < 128) ? (W + (size_t)r * 128) : b;
    float acc = 0.f;
#pragma unroll 4
    for (int k = 0; k < 128; ++k) acc = fmaf(lhs[k], W2[(size_t)k * 128 + j], acc);
    wc[gid] = acc;
}

// ---------------------------------------------------------------------------
extern "C" void kernel_launch(void* const* d_in, const int* in_sizes, int n_in,
                              void* d_out, int out_size, void* d_ws, size_t ws_size,
                              hipStream_t stream) {
    const float* x = (const float*)d_in[0];
    const float* W = (const float*)d_in[1];
    const float* b = (const float*)d_in[2];
    const void* ei = d_in[3];
    const int D = D_MODEL;
    int N = in_sizes[0] / D;
    int E = in_sizes[3] / 2;
    float* out = (float*)d_out;

    char* p = (char*)d_ws;
    size_t off = 0;
    auto take = [&](size_t bytes) {
        void* r = p + off;
        off += (bytes + 255) & ~(size_t)255;
        return r;
    };
    __half2* xh   = (__half2*)take((size_t)N * D * 2);
    __half2* u    = (__half2*)take((size_t)N * D * 2);
    int* csr_src  = (int*)take((size_t)E * 4);
    float* a_arr  = (float*)take((size_t)N * 4);
    float* bfac   = (float*)take((size_t)N * 4);
    float* ab     = (float*)take((size_t)N * 4);
    float* c_arr  = (float*)take((size_t)N * 4);
    int* deg_in   = (int*)take((size_t)N * 4);
    int* offs     = (int*)take((size_t)(N + 1) * 4);
    int* cursor   = (int*)take((size_t)N * 4);
    int* part     = (int*)take(256 * 4);
    float* wc     = (float*)take((size_t)129 * 128 * 4);
    unsigned int* Cpk = (unsigned int*)take((size_t)FC * N * 4);
    int* base     = (int*)take((size_t)FC * N * 4);
    size_t lds_need = off;
    __half2* t2 = xh;   // alias: xh dead once agg<0> completes

    size_t lds_bytes = (size_t)N * 4;
    bool use_lds = (lds_bytes <= 160000) && (lds_need <= ws_size);

    int eb = (E + 255) / 256;
    int G = (N + 1023) / 1024;

    if (use_lds) {
        hist_wc_kernel<<<FC + WCB, 1024, lds_bytes, stream>>>(ei, Cpk, W, b, wc, E, N);
        scanA_xcvt_kernel<<<G, 1024, 0, stream>>>(Cpk, x, a_arr, bfac, ab, deg_in,
                                                  part, (float2*)xh, N);
        scanBC_kernel<<<G, 1024, 0, stream>>>(deg_in, part, Cpk, offs, base, N);
        fill_lds_kernel<<<FC, 1024, lds_bytes, stream>>>(ei, base, csr_src, E, N);
    } else {
        int* rep_out = (int*)Cpk;
        int* rep_in  = (int*)base;
        if (lds_need > ws_size) {
            rep_out = (int*)u;
            rep_in  = (int*)((char*)u + (size_t)NREP * N * 4);
        }
        hipMemsetAsync(rep_out, 0, (size_t)NREP * N * 4, stream);
        hipMemsetAsync(rep_in, 0, (size_t)NREP * N * 4, stream);
        hipMemsetAsync(cursor, 0, (size_t)N * 4, stream);
        wc_plain_kernel<<<(129 * 128 + 255) / 256, 256, 0, stream>>>(W, b, wc);
        prep_kernel<<<eb, 256, 0, stream>>>(ei, rep_out, rep_in, E, N);
        deg_reduce_rep_kernel<<<(N + 255) / 256, 256, 0, stream>>>(rep_out, rep_in, a_arr,
                                                                   bfac, ab, deg_in, N);
        scanA_plain_kernel<<<G, 1024, 0, stream>>>(deg_in, part, N);
        scanC_plain_kernel<<<G, 1024, 0, stream>>>(deg_in, part, offs, N);
        fill_kernel<<<eb, 256, 0, stream>>>(ei, offs, cursor, csr_src, E);
        int n4 = N * (D / 4);
        xcvt_kernel<<<(n4 + 255) / 256, 256, 0, stream>>>(x, a_arr, (float2*)xh, n4);
    }

    agg_kernel<0><<<(N + 3) / 4, 256, 0, stream>>>(xh, offs, csr_src, ab, bfac, a_arr,
                                                   u, c_arr, N);
    agg_kernel<1><<<(N + 3) / 4, 256, 0, stream>>>(u, offs, csr_src, ab, bfac, a_arr,
                                                   t2, c_arr, N);
    gemm_final_kernel<<<(N + 31) / 32, 256, 0, stream>>>(t2, wc, bfac, c_arr,
                                                         b + 128, out, N);
}